// Round 6
// baseline (179.426 us; speedup 1.0000x reference)
//
#include <hip/hip_runtime.h>
#include <math.h>

constexpr int B = 2, S = 512, V = 151643;
constexpr int NROWS = B * S;           // 1024
constexpr float TEMP = 2.0f;
constexpr float CE_W = 1.0f, KL_W = 0.5f;
constexpr int BLK = 256;               // 4 waves; 1024 blocks = 4 blocks/CU
// Row byte size = 606,572 ≡ 12 (mod 16) -> head floats per row h ∈ {0,1,2,3}.
// Aligned region: N4 = 37910 float4s for every h; tail floats = 3 - h.
constexpr int N4 = 37910;
constexpr int MAIN4 = (N4 / (2 * BLK)) * (2 * BLK);   // 37888 (74 iters), rem 22

// Fully fused: one block per (b,s) row streams the row (16B-aligned wide loads),
// reduces {m, s, sT, sumx} with defer-max, forms its CE/KL contributions, and
// atomically accumulates into accs[0..3]; the last block writes out[0].
// accs[0..4] (ce_n, ce_d, kl_n, kl_d, counter) zeroed via hipMemsetAsync.
__global__ __launch_bounds__(BLK) void fused_kernel(
    const float* __restrict__ logits,
    const int*   __restrict__ labels,
    const int*   __restrict__ amask,
    const float* __restrict__ tlp,
    float* __restrict__ accs,
    float* __restrict__ out)
{
    const int row = blockIdx.x;
    const float* __restrict__ x = logits + (size_t)row * V;
    const int tid = threadIdx.x;

    const int off  = (int)((uintptr_t)x & 15);
    const int head = ((16 - off) & 15) >> 2;          // 0..3 floats to align
    const float* __restrict__ xa = x + head;          // 16B-aligned
    const float4* __restrict__ xa4 = reinterpret_cast<const float4*>(xa);

    // early scattered loads (used only in the tid==0 epilogue)
    int lab = 0; float xl = 0.f, tlpv = 0.f; int mskI = 0;
    if (tid == 0) {
        lab  = labels[row];
        xl   = x[lab < 0 ? 0 : lab];
        tlpv = tlp[row & (S - 1)];
        mskI = amask[row];
    }

    float m = -INFINITY, mthr = -INFINITY;
    float sA[4], tA[4], uA[4], sB[4], tB[4], uB[4];
    #pragma unroll
    for (int j = 0; j < 4; ++j) {
        sA[j] = tA[j] = uA[j] = 0.f;
        sB[j] = tB[j] = uB[j] = 0.f;
    }

    auto upd = [&](float xv, float& sS, float& tS, float& uS) {
        uS += xv;
        if (xv > mthr) {                      // rare (~once per lane)
            float r  = __expf((m - xv) * 0.5f);  // exp(-inf)=0 on first hit
            float r2 = r * r;
            #pragma unroll
            for (int j = 0; j < 4; ++j) {
                tA[j] *= r;  sA[j] *= r2;
                tB[j] *= r;  sB[j] *= r2;
            }
            m = xv; mthr = xv + 8.0f;
        }
        float e = __expf((xv - m) * 0.5f);    // <= e^4
        tS += e;
        sS = fmaf(e, e, sS);
    };

    // head floats (0..3, divergent over first few lanes only)
    if (tid < head) upd(x[tid], sB[0], tB[0], uB[0]);

    // main: 74 iterations, 2 aligned float4 loads in flight per lane
    for (int i = tid; i < MAIN4; i += 2 * BLK) {
        float4 a = xa4[i];
        float4 b = xa4[i + BLK];
        upd(a.x, sA[0], tA[0], uA[0]);
        upd(a.y, sA[1], tA[1], uA[1]);
        upd(a.z, sA[2], tA[2], uA[2]);
        upd(a.w, sA[3], tA[3], uA[3]);
        upd(b.x, sB[0], tB[0], uB[0]);
        upd(b.y, sB[1], tB[1], uB[1]);
        upd(b.z, sB[2], tB[2], uB[2]);
        upd(b.w, sB[3], tB[3], uB[3]);
    }
    // remainder float4s (22)
    if (MAIN4 + tid < N4) {
        float4 a = xa4[MAIN4 + tid];
        upd(a.x, sA[0], tA[0], uA[0]);
        upd(a.y, sA[1], tA[1], uA[1]);
        upd(a.z, sA[2], tA[2], uA[2]);
        upd(a.w, sA[3], tA[3], uA[3]);
    }
    // tail floats (3 - head)
    if (tid < 3 - head) {
        upd(xa[4 * N4 + tid], sA[0], tA[0], uA[0]);
    }

    // fold 8 slots (same m within a lane)
    float s = 0.f, sT = 0.f, sumx = 0.f;
    #pragma unroll
    for (int j = 0; j < 4; ++j) {
        s    += sA[j] + sB[j];
        sT   += tA[j] + tB[j];
        sumx += uA[j] + uB[j];
    }

    // wave-64 butterfly (exact merge across differing per-lane m)
    #pragma unroll
    for (int offx = 32; offx >= 1; offx >>= 1) {
        float m2  = __shfl_xor(m,    offx, 64);
        float s2  = __shfl_xor(s,    offx, 64);
        float sT2 = __shfl_xor(sT,   offx, 64);
        float sx2 = __shfl_xor(sumx, offx, 64);
        float nm = fmaxf(m, m2);
        float e1 = __expf((m - nm) * 0.5f), e2 = __expf((m2 - nm) * 0.5f);
        s  = s  * (e1 * e1) + s2 * (e2 * e2);
        sT = sT * e1 + sT2 * e2;
        m  = nm;
        sumx += sx2;
    }

    __shared__ float red[4][4];
    const int wave = tid >> 6, lane = tid & 63;
    if (lane == 0) {
        red[wave][0] = m; red[wave][1] = s; red[wave][2] = sT; red[wave][3] = sumx;
    }
    __syncthreads();
    if (tid == 0) {
        m = red[0][0]; s = red[0][1]; sT = red[0][2]; sumx = red[0][3];
        #pragma unroll
        for (int w = 1; w < 4; ++w) {
            float m2 = red[w][0], s2 = red[w][1], sT2 = red[w][2];
            float nm = fmaxf(m, m2);
            float e1 = __expf((m - nm) * 0.5f), e2 = __expf((m2 - nm) * 0.5f);
            s  = s  * (e1 * e1) + s2 * (e2 * e2);
            sT = sT * e1 + sT2 * e2;
            m  = nm;
            sumx += red[w][3];
        }
        // per-row scalars
        const float logZ  = m + logf(s);
        const float nllv  = logZ - xl;
        const float logZT = m * (1.0f / TEMP) + logf(sT);
        const float slpsum = sumx * (1.0f / TEMP) - (float)V * logZT;

        const bool valid = (lab != -100);
        const float prob = fminf(expf(tlpv), 0.99f);
        const float p = (1.0f - prob) / (float)V;
        const float kl = ((float)V * p * logf(p)) - p * slpsum;
        const float msk = (float)mskI;

        atomicAdd(&accs[0], valid ? nllv : 0.f);
        atomicAdd(&accs[1], valid ? 1.f : 0.f);
        atomicAdd(&accs[2], kl * msk);
        atomicAdd(&accs[3], msk);
        __threadfence();
        unsigned old = atomicAdd(reinterpret_cast<unsigned*>(&accs[4]), 1u);
        if (old == (unsigned)(NROWS - 1)) {
            __threadfence();
            float a = __hip_atomic_load(&accs[0], __ATOMIC_RELAXED, __HIP_MEMORY_SCOPE_AGENT);
            float b = __hip_atomic_load(&accs[1], __ATOMIC_RELAXED, __HIP_MEMORY_SCOPE_AGENT);
            float c = __hip_atomic_load(&accs[2], __ATOMIC_RELAXED, __HIP_MEMORY_SCOPE_AGENT);
            float d = __hip_atomic_load(&accs[3], __ATOMIC_RELAXED, __HIP_MEMORY_SCOPE_AGENT);
            const float ce  = a / fmaxf(b, 1.0f);
            const float klv = (d > 0.f ? c / d : c) * (TEMP * TEMP);
            out[0] = CE_W * ce + KL_W * klv;
        }
    }
}

extern "C" void kernel_launch(void* const* d_in, const int* in_sizes, int n_in,
                              void* d_out, int out_size, void* d_ws, size_t ws_size,
                              hipStream_t stream) {
    const float* logits = (const float*)d_in[0];
    const float* tlp    = (const float*)d_in[1];
    const int*   labels = (const int*)d_in[2];
    const int*   amask  = (const int*)d_in[3];
    float* out  = (float*)d_out;
    float* accs = (float*)d_ws;        // 5 floats: ce_n, ce_d, kl_n, kl_d, counter

    hipMemsetAsync(accs, 0, 5 * sizeof(float), stream);
    fused_kernel<<<NROWS, BLK, 0, stream>>>(logits, labels, amask, tlp, accs, out);
}

// Round 7
// 115.094 us; speedup vs baseline: 1.5590x; 1.5590x over previous
//
#include <hip/hip_runtime.h>
#include <math.h>

constexpr int B = 2, S = 512, V = 151643;
constexpr int NROWS = B * S;           // 1024
constexpr float TEMP = 2.0f;
constexpr float CE_W = 1.0f, KL_W = 0.5f;
constexpr int BLK = 256;               // 4 waves; 1024 blocks = 4 blocks/CU
// Row byte size = 606,572 ≡ 12 (mod 16) -> head floats per row h ∈ {0,1,2,3}.
// After skipping h floats the remaining count is 151643-h >= 151640 = 4*37910,
// so N4 = 37910 aligned float4s for every h; tail floats = 3 - h.
constexpr int N4 = 37910;
constexpr int MAIN4 = (N4 / (2 * BLK)) * (2 * BLK);   // 37888 (74 iters), rem 22

// One block per (b,s) row. Single streaming pass from a 16B-aligned base,
// defer-max (rescale only when xv > m+8; ~once/lane).
__global__ __launch_bounds__(BLK) void row_stats_kernel(
    const float* __restrict__ logits,
    const int*   __restrict__ labels,
    float* __restrict__ nll_out,
    float* __restrict__ slpsum_out)
{
    const int row = blockIdx.x;
    const float* __restrict__ x = logits + (size_t)row * V;
    const int tid = threadIdx.x;

    const int aoff = (int)((uintptr_t)x & 15);
    const int head = ((16 - aoff) & 15) >> 2;         // 0..3 floats to align
    const float* __restrict__ xa = x + head;          // 16B-aligned
    const float4* __restrict__ xa4 = reinterpret_cast<const float4*>(xa);

    float m = -INFINITY, mthr = -INFINITY;
    float sA[4], tA[4], uA[4], sB[4], tB[4], uB[4];
    #pragma unroll
    for (int j = 0; j < 4; ++j) {
        sA[j] = tA[j] = uA[j] = 0.f;
        sB[j] = tB[j] = uB[j] = 0.f;
    }

    auto upd = [&](float xv, float& sS, float& tS, float& uS) {
        uS += xv;
        if (xv > mthr) {                      // rare (~once per lane)
            float r  = __expf((m - xv) * 0.5f);  // exp(-inf)=0 on first hit
            float r2 = r * r;
            #pragma unroll
            for (int j = 0; j < 4; ++j) {
                tA[j] *= r;  sA[j] *= r2;
                tB[j] *= r;  sB[j] *= r2;
            }
            m = xv; mthr = xv + 8.0f;
        }
        float e = __expf((xv - m) * 0.5f);    // <= e^4
        tS += e;
        sS = fmaf(e, e, sS);
    };

    // head floats (0..3; first few lanes only)
    if (tid < head) upd(x[tid], sB[0], tB[0], uB[0]);

    // main: 74 iterations/lane, 2 aligned float4 loads in flight
    for (int i = tid; i < MAIN4; i += 2 * BLK) {
        float4 a = xa4[i];
        float4 b = xa4[i + BLK];
        upd(a.x, sA[0], tA[0], uA[0]);
        upd(a.y, sA[1], tA[1], uA[1]);
        upd(a.z, sA[2], tA[2], uA[2]);
        upd(a.w, sA[3], tA[3], uA[3]);
        upd(b.x, sB[0], tB[0], uB[0]);
        upd(b.y, sB[1], tB[1], uB[1]);
        upd(b.z, sB[2], tB[2], uB[2]);
        upd(b.w, sB[3], tB[3], uB[3]);
    }
    // remainder float4s (22)
    if (MAIN4 + tid < N4) {
        float4 a = xa4[MAIN4 + tid];
        upd(a.x, sA[0], tA[0], uA[0]);
        upd(a.y, sA[1], tA[1], uA[1]);
        upd(a.z, sA[2], tA[2], uA[2]);
        upd(a.w, sA[3], tA[3], uA[3]);
    }
    // tail floats (3 - head)
    if (tid < 3 - head) {
        upd(xa[4 * N4 + tid], sA[0], tA[0], uA[0]);
    }

    // fold 8 slots (same m within a lane)
    float s = 0.f, sT = 0.f, sumx = 0.f;
    #pragma unroll
    for (int j = 0; j < 4; ++j) {
        s    += sA[j] + sB[j];
        sT   += tA[j] + tB[j];
        sumx += uA[j] + uB[j];
    }

    // wave-64 butterfly (exact merge across differing per-lane m)
    #pragma unroll
    for (int offx = 32; offx >= 1; offx >>= 1) {
        float m2  = __shfl_xor(m,    offx, 64);
        float s2  = __shfl_xor(s,    offx, 64);
        float sT2 = __shfl_xor(sT,   offx, 64);
        float sx2 = __shfl_xor(sumx, offx, 64);
        float nm = fmaxf(m, m2);
        float e1 = __expf((m - nm) * 0.5f), e2 = __expf((m2 - nm) * 0.5f);
        s  = s  * (e1 * e1) + s2 * (e2 * e2);
        sT = sT * e1 + sT2 * e2;
        m  = nm;
        sumx += sx2;
    }

    __shared__ float red[4][4];
    const int wave = tid >> 6, lane = tid & 63;
    if (lane == 0) {
        red[wave][0] = m; red[wave][1] = s; red[wave][2] = sT; red[wave][3] = sumx;
    }
    __syncthreads();
    if (tid == 0) {
        m = red[0][0]; s = red[0][1]; sT = red[0][2]; sumx = red[0][3];
        #pragma unroll
        for (int w = 1; w < 4; ++w) {
            float m2 = red[w][0], s2 = red[w][1], sT2 = red[w][2];
            float nm = fmaxf(m, m2);
            float e1 = __expf((m - nm) * 0.5f), e2 = __expf((m2 - nm) * 0.5f);
            s  = s  * (e1 * e1) + s2 * (e2 * e2);
            sT = sT * e1 + sT2 * e2;
            m  = nm;
            sumx += red[w][3];
        }
        const float logZ = m + logf(s);              // log-sum-exp, temp 1
        const int lab  = labels[row];
        const int safe = lab < 0 ? 0 : lab;
        nll_out[row] = logZ - x[safe];
        const float logZT = m * (1.0f / TEMP) + logf(sT);
        slpsum_out[row] = sumx * (1.0f / TEMP) - (float)V * logZT;
    }
}

// One block, 1024 threads: one row per thread, then block reduction.
__global__ __launch_bounds__(1024) void finalize_kernel(
    const float* __restrict__ nll,
    const float* __restrict__ slpsum,
    const int*   __restrict__ labels,
    const int*   __restrict__ amask,
    const float* __restrict__ tlp,
    float* __restrict__ out)
{
    const int t = threadIdx.x;          // NROWS == 1024 == blockDim.x
    const int srow = t % S;             // timestep index

    const int lab = labels[t];
    const bool valid = (lab != -100);
    float ce_n = valid ? nll[t] : 0.f;
    float ce_d = valid ? 1.f : 0.f;

    const float prob = fminf(expf(tlp[srow]), 0.99f);
    const float p = (1.0f - prob) / (float)V;
    const float kl = ((float)V * p * logf(p)) - p * slpsum[t];
    const float msk = (float)amask[t];
    float kl_n = kl * msk;
    float kl_d = msk;

    #pragma unroll
    for (int off = 32; off >= 1; off >>= 1) {
        ce_n += __shfl_xor(ce_n, off, 64);
        ce_d += __shfl_xor(ce_d, off, 64);
        kl_n += __shfl_xor(kl_n, off, 64);
        kl_d += __shfl_xor(kl_d, off, 64);
    }

    __shared__ float red[16][4];
    const int wave = t >> 6, lane = t & 63;
    if (lane == 0) {
        red[wave][0] = ce_n; red[wave][1] = ce_d;
        red[wave][2] = kl_n; red[wave][3] = kl_d;
    }
    __syncthreads();
    if (t == 0) {
        float a = 0.f, b = 0.f, c = 0.f, d = 0.f;
        #pragma unroll
        for (int w = 0; w < 16; ++w) {
            a += red[w][0]; b += red[w][1]; c += red[w][2]; d += red[w][3];
        }
        const float ce  = a / fmaxf(b, 1.0f);
        const float klv = (d > 0.f ? c / d : c) * (TEMP * TEMP);
        out[0] = CE_W * ce + KL_W * klv;
    }
}

extern "C" void kernel_launch(void* const* d_in, const int* in_sizes, int n_in,
                              void* d_out, int out_size, void* d_ws, size_t ws_size,
                              hipStream_t stream) {
    const float* logits = (const float*)d_in[0];
    const float* tlp    = (const float*)d_in[1];
    const int*   labels = (const int*)d_in[2];
    const int*   amask  = (const int*)d_in[3];
    float* out = (float*)d_out;

    float* nll    = (float*)d_ws;
    float* slpsum = nll + NROWS;

    row_stats_kernel<<<NROWS, BLK, 0, stream>>>(logits, labels, nll, slpsum);
    finalize_kernel<<<1, 1024, 0, stream>>>(nll, slpsum, labels, amask, tlp, out);
}